// Round 8
// baseline (137.765 us; speedup 1.0000x reference)
//
#include <hip/hip_runtime.h>
#include <math.h>

typedef _Float16 f16;
typedef _Float16 f16x8 __attribute__((ext_vector_type(8)));
typedef float f32x4 __attribute__((ext_vector_type(4)));

// Problem constants (fixed by reference setup_inputs)
namespace {
constexpr int Bn = 4;     // batch
constexpr int Cn = 64;    // in channels
constexpr int On = 64;    // out channels
constexpr int Hn = 128;
constexpr int Wn = 128;
constexpr int Kn = 9;     // 3x3 taps
constexpr int HWn = Hn * Wn;          // 16384
constexpr int NPIX = Bn * HWn;        // 65536
constexpr int SR = 72;                // padded LDS row stride (halves)
}

// ---------------------------------------------------------------------------
// Transpose x [B][C][H][W] f32 -> xt [B][H*W][C] f16 (channels-last),
// with weight prep folded into the first 144 blocks:
//   wtb [(k*64+o)*64+c] = (f16) weight[(o*64+c)*9+k]   (36864 f16)
//   wofb[(k*32+o)*64+c] = (f16) w_off [(o*64+c)*9+k]   (o<18, else 0; 18432)
// ---------------------------------------------------------------------------
__global__ __launch_bounds__(256) void transpose_prep(
    const float* __restrict__ x, const float* __restrict__ w_off,
    const float* __restrict__ weight, f16* __restrict__ xt,
    f16* __restrict__ wofb, f16* __restrict__ wtb) {
  const int l = threadIdx.x & 63;
  const int cw = threadIdx.x >> 6;          // 0..3
  const int pixbase = blockIdx.x * 64;
  const int b = pixbase >> 14;
  const int hw = (pixbase & (HWn - 1)) + l;

  f16x8 v0, v1;
#pragma unroll
  for (int i = 0; i < 8; ++i) {
    v0[i] = (f16)x[((size_t)(b * Cn + cw * 16 + i)) * HWn + hw];
    v1[i] = (f16)x[((size_t)(b * Cn + cw * 16 + 8 + i)) * HWn + hw];
  }
  f16* dst = xt + ((size_t)(b * HWn + hw)) * 64 + cw * 16;
  *(f16x8*)dst = v0;
  *(f16x8*)(dst + 8) = v1;

  // weight prep tail (first 144 blocks cover 36864 elements)
  if (blockIdx.x < 144) {
    int t = blockIdx.x * 256 + threadIdx.x;
    {
      int c = t & 63, o = (t >> 6) & 63, k = t >> 12;
      wtb[t] = (f16)weight[((o << 6) + c) * 9 + k];
    }
    if (t < Kn * 32 * Cn) {  // 18432
      int c = t & 63, o = (t >> 6) & 31, k = t >> 11;
      float v = (o < 18) ? w_off[((o << 6) + c) * 9 + k] : 0.f;
      wofb[t] = (f16)v;
    }
  }
}

// ---------------------------------------------------------------------------
// Barrier-free fused DCN: block = 1 wave (64 thr) owning 16 consecutive px.
// All LDS is wave-private; DS ops from one wave complete in issue order, so
// no __syncthreads anywhere -> no vmcnt(0) drains; cross-tap loads overlap
// and 12 independent waves/CU (launch_bounds(64,3)) hide latency.
// Phase A: offset conv (18 of 32 padded o) -> off_lds. Per tap: stage
//   S[16px][64c] (integer shift), 4 MFMA (2 m-tiles x 2 k-slices).
// Phase B: main DCN. Per tap: 8 corner loads + 8 W-frags + packed-f16
//   bilinear -> Sb, 8 MFMA (4 m-tiles x 2 k-slices), acc[4] = 64 o x 16 px.
// Staging role: lane l -> px = l>>2, c-chunk = (l&3)*16 (4 lanes = 128 B
// contiguous per sampled row). GEMM role: n=px=l&15, quad q=l>>4.
// ---------------------------------------------------------------------------
__global__ __launch_bounds__(64, 3) void dcn_wave(
    const f16* __restrict__ xt, const f16* __restrict__ wofb,
    const f16* __restrict__ wtb, const float* __restrict__ b_off,
    float* __restrict__ out) {
  __shared__ __align__(16) f16 Sb[2][16 * SR];   // 4608 B, dbuf per tap
  __shared__ float off_lds[16][20];              // 1280 B

  const int l = threadIdx.x;                // 0..63
  const int px_s = l >> 2, cq = l & 3;      // staging role
  const int pixbase = blockIdx.x * 16;
  const int b = pixbase >> 14;
  const int y = (pixbase & (HWn - 1)) >> 7;
  const int xx0 = pixbase & (Wn - 1);       // multiple of 16
  const int xx = xx0 + px_s;
  const f16* xb = xt + ((size_t)b * HWn) * 64;
  const int l15 = l & 15, q = l >> 4;       // gemm role

  // ===================== Phase A: offset conv =====================
  f32x4 accA[2];
#pragma unroll
  for (int m = 0; m < 2; ++m) accA[m] = (f32x4){0.f, 0.f, 0.f, 0.f};

#pragma unroll
  for (int k = 0; k < Kn; ++k) {
    const int dy = k / 3 - 1, dx = k % 3 - 1;
    const int ys = y + dy, xs = xx + dx;
    f16x8 s0 = {}, s1 = {};
    if (ys >= 0 && ys < Hn && xs >= 0 && xs < Wn) {
      const f16* src = xb + (size_t)(ys * Wn + xs) * 64 + cq * 16;
      s0 = *(const f16x8*)src;
      s1 = *(const f16x8*)(src + 8);
    }
    f16x8 wfA[2][2];
#pragma unroll
    for (int m = 0; m < 2; ++m)
#pragma unroll
      for (int s = 0; s < 2; ++s)
        wfA[m][s] = *(const f16x8*)(wofb +
            (((size_t)(k * 32 + m * 16 + l15)) << 6) + s * 32 + q * 8);

    f16* sd = &Sb[k & 1][px_s * SR + cq * 16];
    *(f16x8*)sd = s0;
    *(f16x8*)(sd + 8) = s1;

    f16x8 bf[2];
#pragma unroll
    for (int s = 0; s < 2; ++s)
      bf[s] = *(const f16x8*)&Sb[k & 1][l15 * SR + s * 32 + q * 8];
#pragma unroll
    for (int s = 0; s < 2; ++s)
#pragma unroll
      for (int m = 0; m < 2; ++m)
        accA[m] = __builtin_amdgcn_mfma_f32_16x16x32_f16(wfA[m][s], bf[s],
                                                         accA[m], 0, 0, 0);
  }

  // epilogue A: offsets (+bias) -> wave-private LDS
#pragma unroll
  for (int m = 0; m < 2; ++m)
#pragma unroll
    for (int r = 0; r < 4; ++r) {
      int o = m * 16 + q * 4 + r;
      if (o < 18) off_lds[l15][o] = accA[m][r] + b_off[o];
    }

  float2 off9[9];
#pragma unroll
  for (int k = 0; k < Kn; ++k)
    off9[k] = *(const float2*)&off_lds[px_s][2 * k];

  // ===================== Phase B: main DCN =====================
  f32x4 acc[4];
#pragma unroll
  for (int m = 0; m < 4; ++m) acc[m] = (f32x4){0.f, 0.f, 0.f, 0.f};

#pragma unroll
  for (int k = 0; k < Kn; ++k) {
    const int dy = k / 3 - 1, dx = k % 3 - 1;
    float py = (float)(y + dy) + off9[k].x;
    float pxf = (float)(xx + dx) + off9[k].y;
    float y0f = floorf(py), x0f = floorf(pxf);
    int y0 = (int)y0f, x0 = (int)x0f;
    int y1 = y0 + 1, x1 = x0 + 1;
    float wy1 = py - y0f, wx1 = pxf - x0f;
    float wy0 = 1.f - wy1, wx0 = 1.f - wx1;
    float my0 = (y0 >= 0 && y0 < Hn) ? 1.f : 0.f;
    float my1 = (y1 >= 0 && y1 < Hn) ? 1.f : 0.f;
    float mx0 = (x0 >= 0 && x0 < Wn) ? 1.f : 0.f;
    float mx1 = (x1 >= 0 && x1 < Wn) ? 1.f : 0.f;
    f16 h00 = (f16)(wy0 * wx0 * my0 * mx0);
    f16 h01 = (f16)(wy0 * wx1 * my0 * mx1);
    f16 h10 = (f16)(wy1 * wx0 * my1 * mx0);
    f16 h11 = (f16)(wy1 * wx1 * my1 * mx1);
    int cy0 = min(max(y0, 0), Hn - 1), cy1 = min(max(y1, 0), Hn - 1);
    int cx0 = min(max(x0, 0), Wn - 1), cx1 = min(max(x1, 0), Wn - 1);

    // 8 corner loads issued together (payload in regs, no batching stalls)
    const f16* r00 = xb + (size_t)(cy0 * Wn + cx0) * 64 + cq * 16;
    const f16* r01 = xb + (size_t)(cy0 * Wn + cx1) * 64 + cq * 16;
    const f16* r10 = xb + (size_t)(cy1 * Wn + cx0) * 64 + cq * 16;
    const f16* r11 = xb + (size_t)(cy1 * Wn + cx1) * 64 + cq * 16;
    f16x8 cr[4][2];
#pragma unroll
    for (int h = 0; h < 2; ++h) {
      cr[0][h] = *(const f16x8*)(r00 + h * 8);
      cr[1][h] = *(const f16x8*)(r01 + h * 8);
      cr[2][h] = *(const f16x8*)(r10 + h * 8);
      cr[3][h] = *(const f16x8*)(r11 + h * 8);
    }
    // W A-fragments for all 4 o-tiles
    f16x8 wf[4][2];
#pragma unroll
    for (int m = 0; m < 4; ++m)
#pragma unroll
      for (int s = 0; s < 2; ++s)
        wf[m][s] = *(const f16x8*)(wtb +
            (((size_t)(k * 64 + m * 16 + l15)) << 6) + s * 32 + q * 8);

    f16* sd = &Sb[k & 1][px_s * SR + cq * 16];
#pragma unroll
    for (int h = 0; h < 2; ++h) {
      f16x8 v = cr[0][h] * h00 + cr[1][h] * h01 +
                cr[2][h] * h10 + cr[3][h] * h11;   // v_pk_fma_f16
      *(f16x8*)(sd + h * 8) = v;
    }

    f16x8 bf[2];
#pragma unroll
    for (int s = 0; s < 2; ++s)
      bf[s] = *(const f16x8*)&Sb[k & 1][l15 * SR + s * 32 + q * 8];
#pragma unroll
    for (int s = 0; s < 2; ++s)
#pragma unroll
      for (int m = 0; m < 4; ++m)
        acc[m] = __builtin_amdgcn_mfma_f32_16x16x32_f16(wf[m][s], bf[s],
                                                        acc[m], 0, 0, 0);
  }

  // Epilogue: C/D col=l15 (px), row=q*4+r (o within m-tile)
  float* ob = out + (size_t)b * On * HWn + y * Wn + xx0;
#pragma unroll
  for (int m = 0; m < 4; ++m)
#pragma unroll
    for (int r = 0; r < 4; ++r) {
      int o = m * 16 + q * 4 + r;
      ob[(size_t)o * HWn + l15] = acc[m][r];
    }
}

// ---------------------------------------------------------------------------
extern "C" void kernel_launch(void* const* d_in, const int* in_sizes, int n_in,
                              void* d_out, int out_size, void* d_ws, size_t ws_size,
                              hipStream_t stream) {
  const float* x = (const float*)d_in[0];       // [4,64,128,128]
  const float* w_off = (const float*)d_in[1];   // [18,64,3,3]
  const float* b_off = (const float*)d_in[2];   // [18]
  const float* weight = (const float*)d_in[3];  // [64,64,3,3]
  float* out = (float*)d_out;                   // [4,64,128,128]

  // workspace layout
  f16* xt = (f16*)d_ws;                          // 4,194,304 f16 = 8 MB
  f16* wtb = xt + (size_t)NPIX * Cn;             // 36,864 f16
  f16* wofb = wtb + Kn * On * Cn;                // 18,432 f16

  transpose_prep<<<dim3(NPIX / 64), dim3(256), 0, stream>>>(x, w_off, weight,
                                                            xt, wofb, wtb);
  dcn_wave<<<dim3(NPIX / 16), dim3(64), 0, stream>>>(xt, wofb, wtb, b_off,
                                                     out);
}